// Round 1
// baseline (172.947 us; speedup 1.0000x reference)
//
#include <hip/hip_runtime.h>
#include <math.h>

// Problem constants: N=8192, M=64, K=256, D=16
#define M_SUB 64
#define K_CODES 256
#define D_DIM 16

__global__ __launch_bounds__(256) void pq_quantize_kernel(
    const float* __restrict__ vecs,   // [N, M*D]
    const float* __restrict__ cb,     // [M, K, D]
    float* __restrict__ out,          // [N, M*D]
    int n_rows)
{
    const int m = blockIdx.y;                       // wave-uniform subspace
    const int n = blockIdx.x * 256 + threadIdx.x;   // one row per thread

    // Precompute -||c_k||^2 for this m into LDS (one code per thread).
    __shared__ float nc2[K_CODES];
    {
        const int k = threadIdx.x;
        const float* cp = cb + ((size_t)m * K_CODES + k) * D_DIM;
        float s = 0.f;
        #pragma unroll
        for (int d = 0; d < D_DIM; ++d) s = fmaf(cp[d], cp[d], s);
        nc2[k] = -s;
    }
    __syncthreads();

    if (n >= n_rows) return;

    // Load this thread's sub-vector, pre-scale by 2 (exact in fp).
    const float* vrow = vecs + (size_t)n * (M_SUB * D_DIM) + m * D_DIM;
    float vp[D_DIM];
    {
        const float4* v4 = (const float4*)vrow;
        #pragma unroll
        for (int q = 0; q < 4; ++q) {
            float4 t = v4[q];
            vp[q * 4 + 0] = 2.0f * t.x;
            vp[q * 4 + 1] = 2.0f * t.y;
            vp[q * 4 + 2] = 2.0f * t.z;
            vp[q * 4 + 3] = 2.0f * t.w;
        }
    }

    // Fast path: fp32 scan with top-2 tracking.
    // score_k = 2*v.c_k - ||c_k||^2  (v^2 term constant over k -> dropped)
    float best = -INFINITY, best2 = -INFINITY;
    int bidx = 0;
    for (int k = 0; k < K_CODES; ++k) {
        const float* cp = cb + ((size_t)m * K_CODES + k) * D_DIM;  // uniform -> s_load
        float acc = nc2[k];
        #pragma unroll
        for (int d = 0; d < D_DIM; ++d) acc = fmaf(vp[d], cp[d], acc);
        best2 = fmaxf(best2, fminf(acc, best));
        if (acc > best) { best = acc; bidx = k; }
    }

    // Rare near-tie: fp64 re-scan for an exact argmax (first-index tie-break).
    if (!(best - best2 > 1e-3f)) {
        double vd[D_DIM];
        #pragma unroll
        for (int d = 0; d < D_DIM; ++d) vd[d] = (double)vrow[d];
        double bs = -1e300;
        int bi = 0;
        for (int k = 0; k < K_CODES; ++k) {
            const float* cp = cb + ((size_t)m * K_CODES + k) * D_DIM;
            double vc = 0.0, c2 = 0.0;
            #pragma unroll
            for (int d = 0; d < D_DIM; ++d) {
                double cd = (double)cp[d];
                vc = fma(vd[d], cd, vc);
                c2 = fma(cd, cd, c2);
            }
            double s = 2.0 * vc - c2;
            if (s > bs) { bs = s; bi = k; }
        }
        bidx = bi;
    }

    // Copy the winning code to the output (exact values).
    const float4* src = (const float4*)(cb + ((size_t)m * K_CODES + bidx) * D_DIM);
    float4* dst = (float4*)(out + (size_t)n * (M_SUB * D_DIM) + m * D_DIM);
    #pragma unroll
    for (int q = 0; q < 4; ++q) dst[q] = src[q];
}

extern "C" void kernel_launch(void* const* d_in, const int* in_sizes, int n_in,
                              void* d_out, int out_size, void* d_ws, size_t ws_size,
                              hipStream_t stream) {
    const float* vecs = (const float*)d_in[0];
    const float* cb   = (const float*)d_in[1];
    float* out        = (float*)d_out;
    const int n_rows  = in_sizes[0] / (M_SUB * D_DIM);   // 8192

    dim3 grid((n_rows + 255) / 256, M_SUB);
    pq_quantize_kernel<<<grid, dim3(256), 0, stream>>>(vecs, cb, out, n_rows);
}

// Round 2
// 163.361 us; speedup vs baseline: 1.0587x; 1.0587x over previous
//
#include <hip/hip_runtime.h>
#include <math.h>

// Problem constants: N=8192, M=64, K=256, D=16
#define M_SUB 64
#define K_CODES 256
#define D_DIM 16

__global__ __launch_bounds__(256, 8) void pq_quantize_kernel(
    const float* __restrict__ vecs,   // [N, M*D]
    const float* __restrict__ cb,     // [M, K, D]
    float* __restrict__ out,          // [N, M*D]
    int n_rows)
{
    const int m   = blockIdx.y;                     // wave-uniform subspace
    const int tid = threadIdx.x;
    const int n   = blockIdx.x * 256 + tid;         // one row per thread

    // ---- Stage codebook slice for this m into LDS (16 KB) ----
    __shared__ float cbs[K_CODES * D_DIM];          // [k][d] linear
    __shared__ float nc2[K_CODES];                  // -||c_k||^2
    {
        // thread t copies code k=t (16 floats = 4x float4), coalesced enough
        const float4* src4 = (const float4*)(cb + ((size_t)m * K_CODES + tid) * D_DIM);
        float4* dst4 = (float4*)(cbs + tid * D_DIM);
        float s = 0.f;
        #pragma unroll
        for (int q = 0; q < 4; ++q) {
            float4 t4 = src4[q];
            dst4[q] = t4;
            s = fmaf(t4.x, t4.x, s);
            s = fmaf(t4.y, t4.y, s);
            s = fmaf(t4.z, t4.z, s);
            s = fmaf(t4.w, t4.w, s);
        }
        nc2[tid] = -s;
    }
    __syncthreads();

    if (n >= n_rows) return;

    // ---- Load this thread's sub-vector, pre-scale by 2 (exact) ----
    const float* vrow = vecs + (size_t)n * (M_SUB * D_DIM) + m * D_DIM;
    float vp[D_DIM];
    {
        const float4* v4 = (const float4*)vrow;
        #pragma unroll
        for (int q = 0; q < 4; ++q) {
            float4 t = v4[q];
            vp[q * 4 + 0] = 2.0f * t.x;
            vp[q * 4 + 1] = 2.0f * t.y;
            vp[q * 4 + 2] = 2.0f * t.z;
            vp[q * 4 + 3] = 2.0f * t.w;
        }
    }

    // ---- fp32 scan, 4 codes at a time (ILP=4), top-2 tracking ----
    // Per-k numerics identical to the passing R1 kernel:
    //   acc = -||c_k||^2; then fmaf over d ascending; best/best2 updated in k order.
    const float4* cbs4 = (const float4*)cbs;
    const float4* nc24 = (const float4*)nc2;
    float best = -INFINITY, best2 = -INFINITY;
    int bidx = 0;
    for (int k = 0; k < K_CODES; k += 4) {
        float4 nco = nc24[k >> 2];
        float a0 = nco.x, a1 = nco.y, a2 = nco.z, a3 = nco.w;
        #pragma unroll
        for (int q = 0; q < 4; ++q) {
            float4 c0 = cbs4[(k + 0) * 4 + q];
            float4 c1 = cbs4[(k + 1) * 4 + q];
            float4 c2 = cbs4[(k + 2) * 4 + q];
            float4 c3 = cbs4[(k + 3) * 4 + q];
            a0 = fmaf(vp[q*4+0], c0.x, a0); a0 = fmaf(vp[q*4+1], c0.y, a0);
            a0 = fmaf(vp[q*4+2], c0.z, a0); a0 = fmaf(vp[q*4+3], c0.w, a0);
            a1 = fmaf(vp[q*4+0], c1.x, a1); a1 = fmaf(vp[q*4+1], c1.y, a1);
            a1 = fmaf(vp[q*4+2], c1.z, a1); a1 = fmaf(vp[q*4+3], c1.w, a1);
            a2 = fmaf(vp[q*4+0], c2.x, a2); a2 = fmaf(vp[q*4+1], c2.y, a2);
            a2 = fmaf(vp[q*4+2], c2.z, a2); a2 = fmaf(vp[q*4+3], c2.w, a2);
            a3 = fmaf(vp[q*4+0], c3.x, a3); a3 = fmaf(vp[q*4+1], c3.y, a3);
            a3 = fmaf(vp[q*4+2], c3.z, a3); a3 = fmaf(vp[q*4+3], c3.w, a3);
        }
        // sequential (k-order) top-2 update, identical semantics to R1
        best2 = fmaxf(best2, fminf(a0, best));
        if (a0 > best) { best = a0; bidx = k + 0; }
        best2 = fmaxf(best2, fminf(a1, best));
        if (a1 > best) { best = a1; bidx = k + 1; }
        best2 = fmaxf(best2, fminf(a2, best));
        if (a2 > best) { best = a2; bidx = k + 2; }
        best2 = fmaxf(best2, fminf(a3, best));
        if (a3 > best) { best = a3; bidx = k + 3; }
    }

    // ---- Rare near-tie: fp64 re-scan, register-light (reload vrow per use) ----
    if (!(best - best2 > 1e-3f)) {
        double bs = -1e300;
        int bi = 0;
        for (int k = 0; k < K_CODES; ++k) {
            const float* cp = cbs + k * D_DIM;   // bit-exact copy of cb
            double vc = 0.0, c2d = 0.0;
            #pragma unroll
            for (int d = 0; d < D_DIM; ++d) {
                double cd = (double)cp[d];
                vc  = fma((double)vrow[d], cd, vc);
                c2d = fma(cd, cd, c2d);
            }
            double s = 2.0 * vc - c2d;
            if (s > bs) { bs = s; bi = k; }
        }
        bidx = bi;
    }

    // ---- Copy the winning code (bit-exact, from LDS) to output ----
    const float4* src = (const float4*)(cbs + bidx * D_DIM);
    float4* dst = (float4*)(out + (size_t)n * (M_SUB * D_DIM) + m * D_DIM);
    #pragma unroll
    for (int q = 0; q < 4; ++q) dst[q] = src[q];
}

extern "C" void kernel_launch(void* const* d_in, const int* in_sizes, int n_in,
                              void* d_out, int out_size, void* d_ws, size_t ws_size,
                              hipStream_t stream) {
    const float* vecs = (const float*)d_in[0];
    const float* cb   = (const float*)d_in[1];
    float* out        = (float*)d_out;
    const int n_rows  = in_sizes[0] / (M_SUB * D_DIM);   // 8192

    dim3 grid((n_rows + 255) / 256, M_SUB);
    pq_quantize_kernel<<<grid, dim3(256), 0, stream>>>(vecs, cb, out, n_rows);
}